// Round 5
// baseline (1446.679 us; speedup 1.0000x reference)
//
#include <hip/hip_runtime.h>
#include <hip/hip_bf16.h>

#define BATCH 16384
#define INF 768
#define OUTF 768
#define NSLAB 9                  // slab order per ib: {8=silu, 0..7=rbf}
#define KTOT (NSLAB * INF)       // 6912
#define BM 128
#define BN 128
#define BK 64
#define KB_TILES (INF / BK)      // 12
#define NIT (NSLAB * KB_TILES)   // 108

#define LOG2E 1.4426950408889634f
#define EXPM2 0.13533528323661270f   // exp(-2)

typedef __bf16 bf16x8 __attribute__((ext_vector_type(8)));
typedef float f32x4 __attribute__((ext_vector_type(4)));
typedef unsigned short ushort8v __attribute__((ext_vector_type(8)));

__device__ __forceinline__ unsigned short f2bf(float f) {
  unsigned u = __builtin_bit_cast(unsigned, f);
  u += 0x7fffu + ((u >> 16) & 1u);     // RTNE
  return (unsigned short)(u >> 16);
}

__device__ __forceinline__ unsigned cvt2(float a, float b) {
  __hip_bfloat162 h = __float22bfloat162_rn(make_float2(a, b));  // v_cvt_pk_bf16_f32
  unsigned r;
  __builtin_memcpy(&r, &h, 4);
  return r;
}

__device__ __forceinline__ bf16x8 pack8(const f32x4 a, const f32x4 b) {
  union { uint4 u; bf16x8 v; } r;
  r.u.x = cvt2(a[0], a[1]); r.u.y = cvt2(a[2], a[3]);
  r.u.z = cvt2(b[0], b[1]); r.u.w = cvt2(b[2], b[3]);
  return r.v;
}

__device__ __forceinline__ void gload_lds16(const void* g, void* l) {
  __builtin_amdgcn_global_load_lds(
      (const __attribute__((address_space(1))) unsigned int*)g,
      (__attribute__((address_space(3))) unsigned int*)l, 16, 0, 0);
}

// ---------------- kernel 1: build W_ext (bf16) into workspace ----------------
__global__ __launch_bounds__(256) void build_bext(
    const float* __restrict__ w_b, const float* __restrict__ w_s,
    const float* __restrict__ c, unsigned short* __restrict__ bext) {
  const int tid = blockIdx.x * 256 + threadIdx.x;
  const int o = tid / (KTOT / 8);
  const int k = (tid - o * (KTOT / 8)) * 8;
  const int a = k / INF;
  const int i = k - a * INF;
  float4 v0, v1;
  if (a < 8) {
    const float* cp = c + ((size_t)(a * OUTF + o)) * INF + i;
    const float* wp = w_s + (size_t)o * INF + i;
    const float4 c0 = *(const float4*)cp, c1 = *(const float4*)(cp + 4);
    const float4 s0 = *(const float4*)wp, s1 = *(const float4*)(wp + 4);
    v0 = make_float4(c0.x * s0.x, c0.y * s0.y, c0.z * s0.z, c0.w * s0.w);
    v1 = make_float4(c1.x * s1.x, c1.y * s1.y, c1.z * s1.z, c1.w * s1.w);
  } else {
    const float* bp = w_b + (size_t)o * INF + i;
    v0 = *(const float4*)bp;
    v1 = *(const float4*)(bp + 4);
  }
  ushort8v r;
  r[0] = f2bf(v0.x); r[1] = f2bf(v0.y); r[2] = f2bf(v0.z); r[3] = f2bf(v0.w);
  r[4] = f2bf(v1.x); r[5] = f2bf(v1.y); r[6] = f2bf(v1.z); r[7] = f2bf(v1.w);
  *(ushort8v*)(bext + (size_t)o * KTOT + k) = r;
}

// ------ kernel 2: A fully in registers (recurrence -> cvt_pk -> MFMA),
//        B double-buffered via global_load_lds, 1 barrier/iter, 3 blocks/CU ---
__global__ __launch_bounds__(256, 3) void kan_gemm4(
    const float* __restrict__ x, const unsigned short* __restrict__ bext,
    float* __restrict__ out) {
  __shared__ unsigned short Bs[2][BN * BK];   // 2 x 16 KiB, XOR-swizzled layout

  const int orig = blockIdx.x;
  const int bid = (orig & 7) * 96 + (orig >> 3);   // bijective XCD swizzle (768=8*96)
  const int cb = bid / (BATCH / BM);               // cb-major: XCD chunk shares B-strip
  const int rb = bid - cb * (BATCH / BM);
  const int row0 = rb * BM, col0 = cb * BN;

  const int t = threadIdx.x;
  const int lane = t & 63;
  const int w = t >> 6;                            // wave w owns rows w*32 .. w*32+31
  const int lrow = lane & 15, lhi = lane >> 4;
  const int rgrp = lane >> 3, ch = lane & 7;       // B staging lane decomposition

  f32x4 acc[2][8];   // [mt][n]: 32x128 output per wave
#pragma unroll
  for (int mt = 0; mt < 2; ++mt)
#pragma unroll
    for (int n = 0; n < 8; ++n)
      acc[mt][n] = (f32x4){0.f, 0.f, 0.f, 0.f};

  // B global src pre-swizzled (chunk ^ row) so linear LDS realizes XOR layout.
  const unsigned short* gB0 =
      bext + (size_t)(col0 + w * 32 + rgrp) * KTOT + (size_t)(ch ^ rgrp) * 8;

  auto stage_b = [&](int kt, int bb) {
    const unsigned short* gB = gB0 + (size_t)kt * BK;
    unsigned short* l = &Bs[bb][w * 2048];
#pragma unroll
    for (int q = 0; q < 4; ++q)
      gload_lds16(gB + (size_t)q * 8 * KTOT, l + q * 512);
  };

  // per-lane x row bases: MFMA A-fragment rows (mt*16 + lrow)
  const float* xr0 = x + (size_t)(row0 + w * 32 + lrow) * INF;
  const float* xr1 = xr0 + 16 * INF;

  f32x4 ph[2][2][2], gg[2][2][2];   // [mt][kk][half]: recurrence state
  f32x4 xn[2][2][2];                // x prefetch for next slab-8 (same indexing)

  // prologue: prefetch x(ib=0), stage B for (slab 8, ib 0)
#pragma unroll
  for (int mt = 0; mt < 2; ++mt)
#pragma unroll
    for (int kk = 0; kk < 2; ++kk) {
      const float* p = (mt ? xr1 : xr0) + kk * 32 + lhi * 8;
      xn[mt][kk][0] = *(const f32x4*)p;
      xn[mt][kk][1] = *(const f32x4*)(p + 4);
    }
  stage_b(8 * KB_TILES, 0);

  int s_c = 8, ib_c = 0;   // current slab / i0-block; per-ib order: 8,0,1,...,7
  for (int it = 0; it < NIT; ++it) {
    const int cur = it & 1;
    __syncthreads();   // buf[cur] staged (vmcnt drained) & buf[cur^1] free

    // issue next B stage immediately (full iteration to land)
    if (it < NIT - 1) {
      int s_n, ib_n;
      if (s_c == 8)      { s_n = 0;       ib_n = ib_c; }
      else if (s_c == 7) { s_n = 8;       ib_n = ib_c + 1; }
      else               { s_n = s_c + 1; ib_n = ib_c; }
      stage_b(s_n * KB_TILES + ib_n, cur ^ 1);
    }

    // ---- A fragments from registers ----
    bf16x8 af[2][2];
    if (s_c == 8) {
      // consume prefetched x: silu fragment + recurrence init
#pragma unroll
      for (int mt = 0; mt < 2; ++mt)
#pragma unroll
        for (int kk = 0; kk < 2; ++kk) {
          const f32x4 x0 = xn[mt][kk][0], x1 = xn[mt][kk][1];
          f32x4 s0, s1;
#pragma unroll
          for (int e = 0; e < 4; ++e) {
            s0[e] = x0[e] * __builtin_amdgcn_rcpf(
                        1.f + __builtin_amdgcn_exp2f(x0[e] * (-LOG2E)));
            s1[e] = x1[e] * __builtin_amdgcn_rcpf(
                        1.f + __builtin_amdgcn_exp2f(x1[e] * (-LOG2E)));
          }
          af[mt][kk] = pack8(s0, s1);
          const f32x4 z0 = x0 * 1.75f + 3.5f;   // (x - g0)/h
          const f32x4 z1 = x1 * 1.75f + 3.5f;
#pragma unroll
          for (int e = 0; e < 4; ++e) {
            ph[mt][kk][0][e] = __builtin_amdgcn_exp2f(-(z0[e] * z0[e]) * LOG2E);
            ph[mt][kk][1][e] = __builtin_amdgcn_exp2f(-(z1[e] * z1[e]) * LOG2E);
            gg[mt][kk][0][e] = __builtin_amdgcn_exp2f(z0[e] * (2.f * LOG2E) - LOG2E);
            gg[mt][kk][1][e] = __builtin_amdgcn_exp2f(z1[e] * (2.f * LOG2E) - LOG2E);
          }
        }
    } else {
      if (s_c == 0 && ib_c + 1 < KB_TILES) {
        // prefetch x for next ib (consumed 8 iterations later)
#pragma unroll
        for (int mt = 0; mt < 2; ++mt)
#pragma unroll
          for (int kk = 0; kk < 2; ++kk) {
            const float* p = (mt ? xr1 : xr0) + (ib_c + 1) * BK + kk * 32 + lhi * 8;
            xn[mt][kk][0] = *(const f32x4*)p;
            xn[mt][kk][1] = *(const f32x4*)(p + 4);
          }
      }
#pragma unroll
      for (int mt = 0; mt < 2; ++mt)
#pragma unroll
        for (int kk = 0; kk < 2; ++kk) {
          af[mt][kk] = pack8(ph[mt][kk][0], ph[mt][kk][1]);
          ph[mt][kk][0] *= gg[mt][kk][0];   // phi_{a+1} = phi_a * G_a
          ph[mt][kk][1] *= gg[mt][kk][1];
          gg[mt][kk][0] = gg[mt][kk][0] * EXPM2;   // G_{a+1} = G_a * exp(-2)
          gg[mt][kk][1] = gg[mt][kk][1] * EXPM2;
        }
    }

    // ---- B fragments from LDS + MFMA ----
#pragma unroll
    for (int kk = 0; kk < 2; ++kk) {
      bf16x8 bfr[8];
#pragma unroll
      for (int n = 0; n < 8; ++n) {
        const int rowB = n * 16 + lrow;
        const int chB = (kk * 4 + lhi) ^ (lrow & 7);
        bfr[n] = *(const bf16x8*)&Bs[cur][rowB * 64 + chB * 8];
      }
#pragma unroll
      for (int mt = 0; mt < 2; ++mt)
#pragma unroll
        for (int n = 0; n < 8; ++n)
          acc[mt][n] = __builtin_amdgcn_mfma_f32_16x16x32_bf16(
              af[mt][kk], bfr[n], acc[mt][n], 0, 0, 0);
    }

    // advance slab/ib
    if (s_c == 8)      { s_c = 0; }
    else if (s_c == 7) { s_c = 8; ib_c++; }
    else               { s_c++; }
  }

  // epilogue: C/D layout col=lane&15, row=(lane>>4)*4+r
#pragma unroll
  for (int mt = 0; mt < 2; ++mt) {
#pragma unroll
    for (int n = 0; n < 8; ++n) {
      const int row = row0 + w * 32 + mt * 16 + lhi * 4;
      const int col = col0 + n * 16 + lrow;
#pragma unroll
      for (int r = 0; r < 4; ++r)
        out[(size_t)(row + r) * OUTF + col] = acc[mt][n][r];
    }
  }
}

// ---------------- fallback if ws too small (round-1 kernel) ------------------
#define PK (BK + 8)
__device__ __forceinline__ float phi_f(float x, float g) {
  float z = (x - g) * 1.75f;
  return __expf(-z * z);
}
__device__ __forceinline__ float silu_f(float x) {
  return x / (1.f + __expf(-x));
}

__global__ __launch_bounds__(256, 2) void kan_gemm_fb(
    const float* __restrict__ x, const float* __restrict__ w_b,
    const float* __restrict__ w_s, const float* __restrict__ c,
    float* __restrict__ out) {
  __shared__ unsigned short As[BM][PK];
  __shared__ unsigned short Bs[BN][PK];

  const int bid = blockIdx.x;
  const int cb = bid % (OUTF / BN);
  const int rb = bid / (OUTF / BN);
  const int row0 = rb * BM, col0 = cb * BN;

  const int t = threadIdx.x;
  const int lane = t & 63;
  const int w = t >> 6;
  const int wr = w >> 1, wc = w & 1;
  const int lrow = lane & 15, lhi = lane >> 4;

  f32x4 acc[4][4];
#pragma unroll
  for (int m = 0; m < 4; ++m)
#pragma unroll
    for (int n = 0; n < 4; ++n)
      acc[m][n] = (f32x4){0.f, 0.f, 0.f, 0.f};

  const int rsub = t >> 4;
  const int k4 = t & 15;

  for (int kt = 0; kt < KTOT / BK; ++kt) {
    const int a = kt / KB_TILES;
    const int i0 = (kt % KB_TILES) * BK;
    const float ga = -2.f + (float)a * (4.f / 7.f);

#pragma unroll
    for (int p = 0; p < 8; ++p) {
      const int r = p * 16 + rsub;
      const float4 xv = *(const float4*)(x + (size_t)(row0 + r) * INF + i0 + k4 * 4);
      ushort4 av;
      if (a < 8) {
        av.x = f2bf(phi_f(xv.x, ga)); av.y = f2bf(phi_f(xv.y, ga));
        av.z = f2bf(phi_f(xv.z, ga)); av.w = f2bf(phi_f(xv.w, ga));
      } else {
        av.x = f2bf(silu_f(xv.x)); av.y = f2bf(silu_f(xv.y));
        av.z = f2bf(silu_f(xv.z)); av.w = f2bf(silu_f(xv.w));
      }
      *(ushort4*)&As[r][k4 * 4] = av;

      ushort4 bv;
      if (a < 8) {
        const float4 cv = *(const float4*)(c + ((size_t)a * OUTF + col0 + r) * INF + i0 + k4 * 4);
        const float4 wv = *(const float4*)(w_s + (size_t)(col0 + r) * INF + i0 + k4 * 4);
        bv.x = f2bf(cv.x * wv.x); bv.y = f2bf(cv.y * wv.y);
        bv.z = f2bf(cv.z * wv.z); bv.w = f2bf(cv.w * wv.w);
      } else {
        const float4 bbv = *(const float4*)(w_b + (size_t)(col0 + r) * INF + i0 + k4 * 4);
        bv.x = f2bf(bbv.x); bv.y = f2bf(bbv.y);
        bv.z = f2bf(bbv.z); bv.w = f2bf(bbv.w);
      }
      *(ushort4*)&Bs[r][k4 * 4] = bv;
    }
    __syncthreads();

#pragma unroll
    for (int kk = 0; kk < 2; ++kk) {
      bf16x8 af[4], bfr[4];
#pragma unroll
      for (int m = 0; m < 4; ++m)
        af[m] = *(const bf16x8*)&As[wr * 64 + m * 16 + lrow][kk * 32 + lhi * 8];
#pragma unroll
      for (int n = 0; n < 4; ++n)
        bfr[n] = *(const bf16x8*)&Bs[wc * 64 + n * 16 + lrow][kk * 32 + lhi * 8];
#pragma unroll
      for (int m = 0; m < 4; ++m)
#pragma unroll
        for (int n = 0; n < 4; ++n)
          acc[m][n] = __builtin_amdgcn_mfma_f32_16x16x32_bf16(af[m], bfr[n], acc[m][n], 0, 0, 0);
    }
    __syncthreads();
  }

#pragma unroll
  for (int m = 0; m < 4; ++m) {
#pragma unroll
    for (int n = 0; n < 4; ++n) {
      const int row = row0 + wr * 64 + m * 16 + lhi * 4;
      const int col = col0 + wc * 64 + n * 16 + lrow;
#pragma unroll
      for (int r = 0; r < 4; ++r)
        out[(size_t)(row + r) * OUTF + col] = acc[m][n][r];
    }
  }
}

extern "C" void kernel_launch(void* const* d_in, const int* in_sizes, int n_in,
                              void* d_out, int out_size, void* d_ws, size_t ws_size,
                              hipStream_t stream) {
  const float* x   = (const float*)d_in[0];
  const float* w_b = (const float*)d_in[1];
  const float* w_s = (const float*)d_in[2];
  const float* c   = (const float*)d_in[3];
  float* out = (float*)d_out;

  const size_t need = (size_t)OUTF * KTOT * sizeof(unsigned short);  // 10.1 MiB
  if (ws_size >= need) {
    unsigned short* bext = (unsigned short*)d_ws;
    build_bext<<<(OUTF * KTOT / 8) / 256, 256, 0, stream>>>(w_b, w_s, c, bext);
    kan_gemm4<<<(BATCH / BM) * (OUTF / BN), 256, 0, stream>>>(x, bext, out);
  } else {
    kan_gemm_fb<<<(BATCH / BM) * (OUTF / BN), 256, 0, stream>>>(x, w_b, w_s, c, out);
  }
}

// Round 6
// 255.647 us; speedup vs baseline: 5.6589x; 5.6589x over previous
//
#include <hip/hip_runtime.h>
#include <hip/hip_bf16.h>

#define BATCH 16384
#define INF 768
#define OUTF 768
#define NSLAB 9                  // slab order per ib: {8=silu, 0..7=rbf}
#define KTOT (NSLAB * INF)       // 6912
#define BM 128
#define BN 128
#define BK 64
#define KB_TILES (INF / BK)      // 12
#define NIT (NSLAB * KB_TILES)   // 108

#define LOG2E 1.4426950408889634f
#define EXPM2 0.13533528323661270f   // exp(-2)

typedef __bf16 bf16x8 __attribute__((ext_vector_type(8)));
typedef float f32x4 __attribute__((ext_vector_type(4)));
typedef unsigned short ushort8v __attribute__((ext_vector_type(8)));

__device__ __forceinline__ unsigned short f2bf(float f) {
  unsigned u = __builtin_bit_cast(unsigned, f);
  u += 0x7fffu + ((u >> 16) & 1u);     // RTNE
  return (unsigned short)(u >> 16);
}

__device__ __forceinline__ unsigned cvt2(float a, float b) {
  __hip_bfloat162 h = __float22bfloat162_rn(make_float2(a, b));  // v_cvt_pk_bf16_f32
  unsigned r;
  __builtin_memcpy(&r, &h, 4);
  return r;
}

__device__ __forceinline__ bf16x8 pack8(const f32x4 a, const f32x4 b) {
  union { uint4 u; bf16x8 v; } r;
  r.u.x = cvt2(a[0], a[1]); r.u.y = cvt2(a[2], a[3]);
  r.u.z = cvt2(b[0], b[1]); r.u.w = cvt2(b[2], b[3]);
  return r.v;
}

__device__ __forceinline__ void gload_lds16(const void* g, void* l) {
  __builtin_amdgcn_global_load_lds(
      (const __attribute__((address_space(1))) unsigned int*)g,
      (__attribute__((address_space(3))) unsigned int*)l, 16, 0, 0);
}

// ---------------- kernel 1: build W_ext (bf16) into workspace ----------------
__global__ __launch_bounds__(256) void build_bext(
    const float* __restrict__ w_b, const float* __restrict__ w_s,
    const float* __restrict__ c, unsigned short* __restrict__ bext) {
  const int tid = blockIdx.x * 256 + threadIdx.x;
  const int o = tid / (KTOT / 8);
  const int k = (tid - o * (KTOT / 8)) * 8;
  const int a = k / INF;
  const int i = k - a * INF;
  float4 v0, v1;
  if (a < 8) {
    const float* cp = c + ((size_t)(a * OUTF + o)) * INF + i;
    const float* wp = w_s + (size_t)o * INF + i;
    const float4 c0 = *(const float4*)cp, c1 = *(const float4*)(cp + 4);
    const float4 s0 = *(const float4*)wp, s1 = *(const float4*)(wp + 4);
    v0 = make_float4(c0.x * s0.x, c0.y * s0.y, c0.z * s0.z, c0.w * s0.w);
    v1 = make_float4(c1.x * s1.x, c1.y * s1.y, c1.z * s1.z, c1.w * s1.w);
  } else {
    const float* bp = w_b + (size_t)o * INF + i;
    v0 = *(const float4*)bp;
    v1 = *(const float4*)(bp + 4);
  }
  ushort8v r;
  r[0] = f2bf(v0.x); r[1] = f2bf(v0.y); r[2] = f2bf(v0.z); r[3] = f2bf(v0.w);
  r[4] = f2bf(v1.x); r[5] = f2bf(v1.y); r[6] = f2bf(v1.z); r[7] = f2bf(v1.w);
  *(ushort8v*)(bext + (size_t)o * KTOT + k) = r;
}

// ------ kernel 2: A fully in registers (recurrence -> cvt_pk -> MFMA),
//        B double-buffered via global_load_lds, 1 barrier/iter.
//        launch_bounds(256,2): 2 waves/SIMD cap = 256 VGPRs — state is ~230
//        VGPRs; the (256,3) variant capped at ~170 and spilled acc to scratch
//        (4.9 GB WRITE_SIZE, 5x regression). Spill cliff >> occupancy loss. ---
__global__ __launch_bounds__(256, 2) void kan_gemm4(
    const float* __restrict__ x, const unsigned short* __restrict__ bext,
    float* __restrict__ out) {
  __shared__ unsigned short Bs[2][BN * BK];   // 2 x 16 KiB, XOR-swizzled layout

  const int orig = blockIdx.x;
  const int bid = (orig & 7) * 96 + (orig >> 3);   // bijective XCD swizzle (768=8*96)
  const int cb = bid / (BATCH / BM);               // cb-major: XCD chunk shares B-strip
  const int rb = bid - cb * (BATCH / BM);
  const int row0 = rb * BM, col0 = cb * BN;

  const int t = threadIdx.x;
  const int lane = t & 63;
  const int w = t >> 6;                            // wave w owns rows w*32 .. w*32+31
  const int lrow = lane & 15, lhi = lane >> 4;
  const int rgrp = lane >> 3, ch = lane & 7;       // B staging lane decomposition

  f32x4 acc[2][8];   // [mt][n]: 32x128 output per wave
#pragma unroll
  for (int mt = 0; mt < 2; ++mt)
#pragma unroll
    for (int n = 0; n < 8; ++n)
      acc[mt][n] = (f32x4){0.f, 0.f, 0.f, 0.f};

  // B global src pre-swizzled (chunk ^ row) so linear LDS realizes XOR layout.
  const unsigned short* gB0 =
      bext + (size_t)(col0 + w * 32 + rgrp) * KTOT + (size_t)(ch ^ rgrp) * 8;

  auto stage_b = [&](int kt, int bb) {
    const unsigned short* gB = gB0 + (size_t)kt * BK;
    unsigned short* l = &Bs[bb][w * 2048];
#pragma unroll
    for (int q = 0; q < 4; ++q)
      gload_lds16(gB + (size_t)q * 8 * KTOT, l + q * 512);
  };

  // per-lane x row bases: MFMA A-fragment rows (mt*16 + lrow)
  const float* xr0 = x + (size_t)(row0 + w * 32 + lrow) * INF;
  const float* xr1 = xr0 + 16 * INF;

  f32x4 ph[2][2][2], gg[2][2][2];   // [mt][kk][half]: recurrence state
  f32x4 xn[2][2][2];                // x prefetch for next slab-8 (same indexing)

  // prologue: prefetch x(ib=0), stage B for (slab 8, ib 0)
#pragma unroll
  for (int mt = 0; mt < 2; ++mt)
#pragma unroll
    for (int kk = 0; kk < 2; ++kk) {
      const float* p = (mt ? xr1 : xr0) + kk * 32 + lhi * 8;
      xn[mt][kk][0] = *(const f32x4*)p;
      xn[mt][kk][1] = *(const f32x4*)(p + 4);
    }
  stage_b(8 * KB_TILES, 0);

  int s_c = 8, ib_c = 0;   // current slab / i0-block; per-ib order: 8,0,1,...,7
  for (int it = 0; it < NIT; ++it) {
    const int cur = it & 1;
    __syncthreads();   // buf[cur] staged (vmcnt drained) & buf[cur^1] free

    // issue next B stage immediately (full iteration to land)
    if (it < NIT - 1) {
      int s_n, ib_n;
      if (s_c == 8)      { s_n = 0;       ib_n = ib_c; }
      else if (s_c == 7) { s_n = 8;       ib_n = ib_c + 1; }
      else               { s_n = s_c + 1; ib_n = ib_c; }
      stage_b(s_n * KB_TILES + ib_n, cur ^ 1);
    }

    // ---- A fragments from registers ----
    bf16x8 af[2][2];
    if (s_c == 8) {
      // consume prefetched x: silu fragment + recurrence init
#pragma unroll
      for (int mt = 0; mt < 2; ++mt)
#pragma unroll
        for (int kk = 0; kk < 2; ++kk) {
          const f32x4 x0 = xn[mt][kk][0], x1 = xn[mt][kk][1];
          f32x4 s0, s1;
#pragma unroll
          for (int e = 0; e < 4; ++e) {
            s0[e] = x0[e] * __builtin_amdgcn_rcpf(
                        1.f + __builtin_amdgcn_exp2f(x0[e] * (-LOG2E)));
            s1[e] = x1[e] * __builtin_amdgcn_rcpf(
                        1.f + __builtin_amdgcn_exp2f(x1[e] * (-LOG2E)));
          }
          af[mt][kk] = pack8(s0, s1);
          const f32x4 z0 = x0 * 1.75f + 3.5f;   // (x - g0)/h
          const f32x4 z1 = x1 * 1.75f + 3.5f;
#pragma unroll
          for (int e = 0; e < 4; ++e) {
            ph[mt][kk][0][e] = __builtin_amdgcn_exp2f(-(z0[e] * z0[e]) * LOG2E);
            ph[mt][kk][1][e] = __builtin_amdgcn_exp2f(-(z1[e] * z1[e]) * LOG2E);
            gg[mt][kk][0][e] = __builtin_amdgcn_exp2f(z0[e] * (2.f * LOG2E) - LOG2E);
            gg[mt][kk][1][e] = __builtin_amdgcn_exp2f(z1[e] * (2.f * LOG2E) - LOG2E);
          }
        }
    } else {
      if (s_c == 0 && ib_c + 1 < KB_TILES) {
        // prefetch x for next ib (consumed 8 iterations later)
#pragma unroll
        for (int mt = 0; mt < 2; ++mt)
#pragma unroll
          for (int kk = 0; kk < 2; ++kk) {
            const float* p = (mt ? xr1 : xr0) + (ib_c + 1) * BK + kk * 32 + lhi * 8;
            xn[mt][kk][0] = *(const f32x4*)p;
            xn[mt][kk][1] = *(const f32x4*)(p + 4);
          }
      }
#pragma unroll
      for (int mt = 0; mt < 2; ++mt)
#pragma unroll
        for (int kk = 0; kk < 2; ++kk) {
          af[mt][kk] = pack8(ph[mt][kk][0], ph[mt][kk][1]);
          ph[mt][kk][0] *= gg[mt][kk][0];   // phi_{a+1} = phi_a * G_a
          ph[mt][kk][1] *= gg[mt][kk][1];
          gg[mt][kk][0] = gg[mt][kk][0] * EXPM2;   // G_{a+1} = G_a * exp(-2)
          gg[mt][kk][1] = gg[mt][kk][1] * EXPM2;
        }
    }

    // ---- B fragments from LDS + MFMA ----
#pragma unroll
    for (int kk = 0; kk < 2; ++kk) {
      bf16x8 bfr[8];
#pragma unroll
      for (int n = 0; n < 8; ++n) {
        const int rowB = n * 16 + lrow;
        const int chB = (kk * 4 + lhi) ^ (lrow & 7);
        bfr[n] = *(const bf16x8*)&Bs[cur][rowB * 64 + chB * 8];
      }
#pragma unroll
      for (int mt = 0; mt < 2; ++mt)
#pragma unroll
        for (int n = 0; n < 8; ++n)
          acc[mt][n] = __builtin_amdgcn_mfma_f32_16x16x32_bf16(
              af[mt][kk], bfr[n], acc[mt][n], 0, 0, 0);
    }

    // advance slab/ib
    if (s_c == 8)      { s_c = 0; }
    else if (s_c == 7) { s_c = 8; ib_c++; }
    else               { s_c++; }
  }

  // epilogue: C/D layout col=lane&15, row=(lane>>4)*4+r
#pragma unroll
  for (int mt = 0; mt < 2; ++mt) {
#pragma unroll
    for (int n = 0; n < 8; ++n) {
      const int row = row0 + w * 32 + mt * 16 + lhi * 4;
      const int col = col0 + n * 16 + lrow;
#pragma unroll
      for (int r = 0; r < 4; ++r)
        out[(size_t)(row + r) * OUTF + col] = acc[mt][n][r];
    }
  }
}

// ---------------- fallback if ws too small (round-1 kernel) ------------------
#define PK (BK + 8)
__device__ __forceinline__ float phi_f(float x, float g) {
  float z = (x - g) * 1.75f;
  return __expf(-z * z);
}
__device__ __forceinline__ float silu_f(float x) {
  return x / (1.f + __expf(-x));
}

__global__ __launch_bounds__(256, 2) void kan_gemm_fb(
    const float* __restrict__ x, const float* __restrict__ w_b,
    const float* __restrict__ w_s, const float* __restrict__ c,
    float* __restrict__ out) {
  __shared__ unsigned short As[BM][PK];
  __shared__ unsigned short Bs[BN][PK];

  const int bid = blockIdx.x;
  const int cb = bid % (OUTF / BN);
  const int rb = bid / (OUTF / BN);
  const int row0 = rb * BM, col0 = cb * BN;

  const int t = threadIdx.x;
  const int lane = t & 63;
  const int w = t >> 6;
  const int wr = w >> 1, wc = w & 1;
  const int lrow = lane & 15, lhi = lane >> 4;

  f32x4 acc[4][4];
#pragma unroll
  for (int m = 0; m < 4; ++m)
#pragma unroll
    for (int n = 0; n < 4; ++n)
      acc[m][n] = (f32x4){0.f, 0.f, 0.f, 0.f};

  const int rsub = t >> 4;
  const int k4 = t & 15;

  for (int kt = 0; kt < KTOT / BK; ++kt) {
    const int a = kt / KB_TILES;
    const int i0 = (kt % KB_TILES) * BK;
    const float ga = -2.f + (float)a * (4.f / 7.f);

#pragma unroll
    for (int p = 0; p < 8; ++p) {
      const int r = p * 16 + rsub;
      const float4 xv = *(const float4*)(x + (size_t)(row0 + r) * INF + i0 + k4 * 4);
      ushort4 av;
      if (a < 8) {
        av.x = f2bf(phi_f(xv.x, ga)); av.y = f2bf(phi_f(xv.y, ga));
        av.z = f2bf(phi_f(xv.z, ga)); av.w = f2bf(phi_f(xv.w, ga));
      } else {
        av.x = f2bf(silu_f(xv.x)); av.y = f2bf(silu_f(xv.y));
        av.z = f2bf(silu_f(xv.z)); av.w = f2bf(silu_f(xv.w));
      }
      *(ushort4*)&As[r][k4 * 4] = av;

      ushort4 bv;
      if (a < 8) {
        const float4 cv = *(const float4*)(c + ((size_t)a * OUTF + col0 + r) * INF + i0 + k4 * 4);
        const float4 wv = *(const float4*)(w_s + (size_t)(col0 + r) * INF + i0 + k4 * 4);
        bv.x = f2bf(cv.x * wv.x); bv.y = f2bf(cv.y * wv.y);
        bv.z = f2bf(cv.z * wv.z); bv.w = f2bf(cv.w * wv.w);
      } else {
        const float4 bbv = *(const float4*)(w_b + (size_t)(col0 + r) * INF + i0 + k4 * 4);
        bv.x = f2bf(bbv.x); bv.y = f2bf(bbv.y);
        bv.z = f2bf(bbv.z); bv.w = f2bf(bbv.w);
      }
      *(ushort4*)&Bs[r][k4 * 4] = bv;
    }
    __syncthreads();

#pragma unroll
    for (int kk = 0; kk < 2; ++kk) {
      bf16x8 af[4], bfr[4];
#pragma unroll
      for (int m = 0; m < 4; ++m)
        af[m] = *(const bf16x8*)&As[wr * 64 + m * 16 + lrow][kk * 32 + lhi * 8];
#pragma unroll
      for (int n = 0; n < 4; ++n)
        bfr[n] = *(const bf16x8*)&Bs[wc * 64 + n * 16 + lrow][kk * 32 + lhi * 8];
#pragma unroll
      for (int m = 0; m < 4; ++m)
#pragma unroll
        for (int n = 0; n < 4; ++n)
          acc[m][n] = __builtin_amdgcn_mfma_f32_16x16x32_bf16(af[m], bfr[n], acc[m][n], 0, 0, 0);
    }
    __syncthreads();
  }

#pragma unroll
  for (int m = 0; m < 4; ++m) {
#pragma unroll
    for (int n = 0; n < 4; ++n) {
      const int row = row0 + wr * 64 + m * 16 + lhi * 4;
      const int col = col0 + wc * 64 + n * 16 + lrow;
#pragma unroll
      for (int r = 0; r < 4; ++r)
        out[(size_t)(row + r) * OUTF + col] = acc[m][n][r];
    }
  }
}

extern "C" void kernel_launch(void* const* d_in, const int* in_sizes, int n_in,
                              void* d_out, int out_size, void* d_ws, size_t ws_size,
                              hipStream_t stream) {
  const float* x   = (const float*)d_in[0];
  const float* w_b = (const float*)d_in[1];
  const float* w_s = (const float*)d_in[2];
  const float* c   = (const float*)d_in[3];
  float* out = (float*)d_out;

  const size_t need = (size_t)OUTF * KTOT * sizeof(unsigned short);  // 10.1 MiB
  if (ws_size >= need) {
    unsigned short* bext = (unsigned short*)d_ws;
    build_bext<<<(OUTF * KTOT / 8) / 256, 256, 0, stream>>>(w_b, w_s, c, bext);
    kan_gemm4<<<(BATCH / BM) * (OUTF / BN), 256, 0, stream>>>(x, bext, out);
  } else {
    kan_gemm_fb<<<(BATCH / BM) * (OUTF / BN), 256, 0, stream>>>(x, w_b, w_s, c, out);
  }
}

// Round 7
// 246.614 us; speedup vs baseline: 5.8662x; 1.0366x over previous
//
#include <hip/hip_runtime.h>
#include <hip/hip_bf16.h>

#define BATCH 16384
#define INF 768
#define OUTF 768
#define NSLAB 9                  // slab order per ib: {8=silu, 0..7=rbf}
#define KTOT (NSLAB * INF)       // 6912
#define BM 128
#define BN 128
#define BK 64
#define KB_TILES (INF / BK)      // 12
#define NIT (NSLAB * KB_TILES)   // 108

#define LOG2E 1.4426950408889634f
#define EXPM2 0.13533528323661270f   // exp(-2)

typedef __bf16 bf16x8 __attribute__((ext_vector_type(8)));
typedef float f32x4 __attribute__((ext_vector_type(4)));
typedef unsigned short ushort8v __attribute__((ext_vector_type(8)));

__device__ __forceinline__ unsigned short f2bf(float f) {
  unsigned u = __builtin_bit_cast(unsigned, f);
  u += 0x7fffu + ((u >> 16) & 1u);     // RTNE
  return (unsigned short)(u >> 16);
}

__device__ __forceinline__ unsigned cvt2(float a, float b) {
  __hip_bfloat162 h = __float22bfloat162_rn(make_float2(a, b));  // v_cvt_pk_bf16_f32
  unsigned r;
  __builtin_memcpy(&r, &h, 4);
  return r;
}

__device__ __forceinline__ bf16x8 pack8(const f32x4 a, const f32x4 b) {
  union { uint4 u; bf16x8 v; } r;
  r.u.x = cvt2(a[0], a[1]); r.u.y = cvt2(a[2], a[3]);
  r.u.z = cvt2(b[0], b[1]); r.u.w = cvt2(b[2], b[3]);
  return r.v;
}

__device__ __forceinline__ void gload_lds16(const void* g, void* l) {
  __builtin_amdgcn_global_load_lds(
      (const __attribute__((address_space(1))) unsigned int*)g,
      (__attribute__((address_space(3))) unsigned int*)l, 16, 0, 0);
}

// ---------------- kernel 1: build W_ext (bf16) into workspace ----------------
__global__ __launch_bounds__(256) void build_bext(
    const float* __restrict__ w_b, const float* __restrict__ w_s,
    const float* __restrict__ c, unsigned short* __restrict__ bext) {
  const int tid = blockIdx.x * 256 + threadIdx.x;
  const int o = tid / (KTOT / 8);
  const int k = (tid - o * (KTOT / 8)) * 8;
  const int a = k / INF;
  const int i = k - a * INF;
  float4 v0, v1;
  if (a < 8) {
    const float* cp = c + ((size_t)(a * OUTF + o)) * INF + i;
    const float* wp = w_s + (size_t)o * INF + i;
    const float4 c0 = *(const float4*)cp, c1 = *(const float4*)(cp + 4);
    const float4 s0 = *(const float4*)wp, s1 = *(const float4*)(wp + 4);
    v0 = make_float4(c0.x * s0.x, c0.y * s0.y, c0.z * s0.z, c0.w * s0.w);
    v1 = make_float4(c1.x * s1.x, c1.y * s1.y, c1.z * s1.z, c1.w * s1.w);
  } else {
    const float* bp = w_b + (size_t)o * INF + i;
    v0 = *(const float4*)bp;
    v1 = *(const float4*)(bp + 4);
  }
  ushort8v r;
  r[0] = f2bf(v0.x); r[1] = f2bf(v0.y); r[2] = f2bf(v0.z); r[3] = f2bf(v0.w);
  r[4] = f2bf(v1.x); r[5] = f2bf(v1.y); r[6] = f2bf(v1.z); r[7] = f2bf(v1.w);
  *(ushort8v*)(bext + (size_t)o * KTOT + k) = r;
}

// ------ kernel 2: A in registers; B via 4-deep global_load_lds ring with
//        COUNTED vmcnt (T3/T4): stage(it+3) issued at iter top; iter end waits
//        vmcnt(8) (own stage(it+1) done, FIFO) then s_barrier — two stages stay
//        in flight across barriers, never drained to 0 in the main loop. ------
__global__ __launch_bounds__(256, 2) void kan_gemm5(
    const float* __restrict__ x, const unsigned short* __restrict__ bext,
    float* __restrict__ out) {
  __shared__ unsigned short Bs[4][BN * BK];   // 4 x 16 KiB ring, XOR-swz layout

  const int orig = blockIdx.x;
  const int bid = (orig & 7) * 96 + (orig >> 3);   // bijective XCD swizzle (768=8*96)
  const int cb = bid / (BATCH / BM);               // cb-major: XCD chunk shares B-strip
  const int rb = bid - cb * (BATCH / BM);
  const int row0 = rb * BM, col0 = cb * BN;

  const int t = threadIdx.x;
  const int lane = t & 63;
  const int w = t >> 6;                            // wave w owns rows w*32 .. w*32+31
  const int lrow = lane & 15, lhi = lane >> 4;
  const int rgrp = lane >> 3, ch = lane & 7;       // B staging lane decomposition

  f32x4 acc[2][8];   // [mt][n]: 32x128 output per wave
#pragma unroll
  for (int mt = 0; mt < 2; ++mt)
#pragma unroll
    for (int n = 0; n < 8; ++n)
      acc[mt][n] = (f32x4){0.f, 0.f, 0.f, 0.f};

  // B global src pre-swizzled (chunk ^ row) so linear LDS realizes XOR layout.
  const unsigned short* gB0 =
      bext + (size_t)(col0 + w * 32 + rgrp) * KTOT + (size_t)(ch ^ rgrp) * 8;

  // stage index k (iteration order) -> kt = slab*KB_TILES + ib
  auto kt_of = [&](int k) {
    const int ib = k / 9;
    const int r = k - ib * 9;
    const int s = (r == 0) ? 8 : (r - 1);
    return s * KB_TILES + ib;
  };

  auto stage_b = [&](int k) {
    const unsigned short* gB = gB0 + (size_t)kt_of(k) * BK;
    unsigned short* l = &Bs[k & 3][w * 2048];
#pragma unroll
    for (int q = 0; q < 4; ++q)
      gload_lds16(gB + (size_t)q * 8 * KTOT, l + q * 512);
  };

  // per-lane x row bases: MFMA A-fragment rows (mt*16 + lrow)
  const float* xr0 = x + (size_t)(row0 + w * 32 + lrow) * INF;
  const float* xr1 = xr0 + 16 * INF;

  f32x4 ph[2][2][2], gg[2][2][2];   // [mt][kk][half]: recurrence state
  f32x4 xn[2][2][2];                // x prefetch for next slab-8

  auto load_x = [&](int ib) {
#pragma unroll
    for (int mt = 0; mt < 2; ++mt)
#pragma unroll
      for (int kk = 0; kk < 2; ++kk) {
        const float* p = (mt ? xr1 : xr0) + ib * BK + kk * 32 + lhi * 8;
        xn[mt][kk][0] = *(const f32x4*)p;
        xn[mt][kk][1] = *(const f32x4*)(p + 4);
      }
  };

  // prologue: x(ib0) first (oldest), then stages 0..2.
  // vmcnt(8) => x + stage(0) retired (FIFO); stages 1,2 may remain in flight.
  load_x(0);
  stage_b(0);
  stage_b(1);
  stage_b(2);
  asm volatile("s_waitcnt vmcnt(8)" ::: "memory");
  __builtin_amdgcn_s_barrier();
  __builtin_amdgcn_sched_barrier(0);

  int s_c = 8, ib_c = 0;   // current slab / i0-block; per-ib order: 8,0,1,...,7
  for (int it = 0; it < NIT; ++it) {
    const int cur = it & 3;
    const bool xpf = (s_c == 6) && (ib_c + 1 < KB_TILES);
    if (xpf) load_x(ib_c + 1);           // consumed 2 iters later (next slab-8)
    if (it + 3 < NIT) stage_b(it + 3);   // 2 stages in flight when consuming it

    // ---- A fragments from registers ----
    bf16x8 af[2][2];
    if (s_c == 8) {
      // consume prefetched x: silu fragment + recurrence init
#pragma unroll
      for (int mt = 0; mt < 2; ++mt)
#pragma unroll
        for (int kk = 0; kk < 2; ++kk) {
          const f32x4 x0 = xn[mt][kk][0], x1 = xn[mt][kk][1];
          f32x4 s0, s1;
#pragma unroll
          for (int e = 0; e < 4; ++e) {
            s0[e] = x0[e] * __builtin_amdgcn_rcpf(
                        1.f + __builtin_amdgcn_exp2f(x0[e] * (-LOG2E)));
            s1[e] = x1[e] * __builtin_amdgcn_rcpf(
                        1.f + __builtin_amdgcn_exp2f(x1[e] * (-LOG2E)));
          }
          af[mt][kk] = pack8(s0, s1);
          const f32x4 z0 = x0 * 1.75f + 3.5f;   // (x - g0)/h
          const f32x4 z1 = x1 * 1.75f + 3.5f;
#pragma unroll
          for (int e = 0; e < 4; ++e) {
            ph[mt][kk][0][e] = __builtin_amdgcn_exp2f(-(z0[e] * z0[e]) * LOG2E);
            ph[mt][kk][1][e] = __builtin_amdgcn_exp2f(-(z1[e] * z1[e]) * LOG2E);
            gg[mt][kk][0][e] = __builtin_amdgcn_exp2f(z0[e] * (2.f * LOG2E) - LOG2E);
            gg[mt][kk][1][e] = __builtin_amdgcn_exp2f(z1[e] * (2.f * LOG2E) - LOG2E);
          }
        }
    } else {
#pragma unroll
      for (int mt = 0; mt < 2; ++mt)
#pragma unroll
        for (int kk = 0; kk < 2; ++kk) {
          af[mt][kk] = pack8(ph[mt][kk][0], ph[mt][kk][1]);
          ph[mt][kk][0] *= gg[mt][kk][0];   // phi_{a+1} = phi_a * G_a
          ph[mt][kk][1] *= gg[mt][kk][1];
          gg[mt][kk][0] = gg[mt][kk][0] * EXPM2;   // G_{a+1} = G_a * exp(-2)
          gg[mt][kk][1] = gg[mt][kk][1] * EXPM2;
        }
    }

    // ---- B fragments from LDS + MFMA ----
#pragma unroll
    for (int kk = 0; kk < 2; ++kk) {
      bf16x8 bfr[8];
#pragma unroll
      for (int n = 0; n < 8; ++n) {
        const int rowB = n * 16 + lrow;
        const int chB = (kk * 4 + lhi) ^ (lrow & 7);
        bfr[n] = *(const bf16x8*)&Bs[cur][rowB * 64 + chB * 8];
      }
#pragma unroll
      for (int mt = 0; mt < 2; ++mt)
#pragma unroll
        for (int n = 0; n < 8; ++n)
          acc[mt][n] = __builtin_amdgcn_mfma_f32_16x16x32_bf16(
              af[mt][kk], bfr[n], acc[mt][n], 0, 0, 0);
    }

    // ---- counted pipeline wait (own stage(it+1) done), then barrier ----
    // Queue (FIFO): [st(it+1), st(it+2), x?, st(it+3)] — allow 8 (16 w/ x).
    if (it < NIT - 3) {
      if (xpf) asm volatile("s_waitcnt vmcnt(16)" ::: "memory");
      else     asm volatile("s_waitcnt vmcnt(8)" ::: "memory");
    } else if (it == NIT - 3) {
      asm volatile("s_waitcnt vmcnt(4)" ::: "memory");
    } else if (it == NIT - 2) {
      asm volatile("s_waitcnt vmcnt(0)" ::: "memory");
    }
    if (it < NIT - 1) {
      __builtin_amdgcn_s_barrier();
      __builtin_amdgcn_sched_barrier(0);   // no ds_read hoists above barrier
    }

    // advance slab/ib
    if (s_c == 8)      { s_c = 0; }
    else if (s_c == 7) { s_c = 8; ib_c++; }
    else               { s_c++; }
  }

  // epilogue: C/D layout col=lane&15, row=(lane>>4)*4+r
#pragma unroll
  for (int mt = 0; mt < 2; ++mt) {
#pragma unroll
    for (int n = 0; n < 8; ++n) {
      const int row = row0 + w * 32 + mt * 16 + lhi * 4;
      const int col = col0 + n * 16 + lrow;
#pragma unroll
      for (int r = 0; r < 4; ++r)
        out[(size_t)(row + r) * OUTF + col] = acc[mt][n][r];
    }
  }
}

// ---------------- fallback if ws too small (round-1 kernel) ------------------
#define PK (BK + 8)
__device__ __forceinline__ float phi_f(float x, float g) {
  float z = (x - g) * 1.75f;
  return __expf(-z * z);
}
__device__ __forceinline__ float silu_f(float x) {
  return x / (1.f + __expf(-x));
}

__global__ __launch_bounds__(256, 2) void kan_gemm_fb(
    const float* __restrict__ x, const float* __restrict__ w_b,
    const float* __restrict__ w_s, const float* __restrict__ c,
    float* __restrict__ out) {
  __shared__ unsigned short As[BM][PK];
  __shared__ unsigned short Bs[BN][PK];

  const int bid = blockIdx.x;
  const int cb = bid % (OUTF / BN);
  const int rb = bid / (OUTF / BN);
  const int row0 = rb * BM, col0 = cb * BN;

  const int t = threadIdx.x;
  const int lane = t & 63;
  const int w = t >> 6;
  const int wr = w >> 1, wc = w & 1;
  const int lrow = lane & 15, lhi = lane >> 4;

  f32x4 acc[4][4];
#pragma unroll
  for (int m = 0; m < 4; ++m)
#pragma unroll
    for (int n = 0; n < 4; ++n)
      acc[m][n] = (f32x4){0.f, 0.f, 0.f, 0.f};

  const int rsub = t >> 4;
  const int k4 = t & 15;

  for (int kt = 0; kt < KTOT / BK; ++kt) {
    const int a = kt / KB_TILES;
    const int i0 = (kt % KB_TILES) * BK;
    const float ga = -2.f + (float)a * (4.f / 7.f);

#pragma unroll
    for (int p = 0; p < 8; ++p) {
      const int r = p * 16 + rsub;
      const float4 xv = *(const float4*)(x + (size_t)(row0 + r) * INF + i0 + k4 * 4);
      ushort4 av;
      if (a < 8) {
        av.x = f2bf(phi_f(xv.x, ga)); av.y = f2bf(phi_f(xv.y, ga));
        av.z = f2bf(phi_f(xv.z, ga)); av.w = f2bf(phi_f(xv.w, ga));
      } else {
        av.x = f2bf(silu_f(xv.x)); av.y = f2bf(silu_f(xv.y));
        av.z = f2bf(silu_f(xv.z)); av.w = f2bf(silu_f(xv.w));
      }
      *(ushort4*)&As[r][k4 * 4] = av;

      ushort4 bv;
      if (a < 8) {
        const float4 cv = *(const float4*)(c + ((size_t)a * OUTF + col0 + r) * INF + i0 + k4 * 4);
        const float4 wv = *(const float4*)(w_s + (size_t)(col0 + r) * INF + i0 + k4 * 4);
        bv.x = f2bf(cv.x * wv.x); bv.y = f2bf(cv.y * wv.y);
        bv.z = f2bf(cv.z * wv.z); bv.w = f2bf(cv.w * wv.w);
      } else {
        const float4 bbv = *(const float4*)(w_b + (size_t)(col0 + r) * INF + i0 + k4 * 4);
        bv.x = f2bf(bbv.x); bv.y = f2bf(bbv.y);
        bv.z = f2bf(bbv.z); bv.w = f2bf(bbv.w);
      }
      *(ushort4*)&Bs[r][k4 * 4] = bv;
    }
    __syncthreads();

#pragma unroll
    for (int kk = 0; kk < 2; ++kk) {
      bf16x8 af[4], bfr[4];
#pragma unroll
      for (int m = 0; m < 4; ++m)
        af[m] = *(const bf16x8*)&As[wr * 64 + m * 16 + lrow][kk * 32 + lhi * 8];
#pragma unroll
      for (int n = 0; n < 4; ++n)
        bfr[n] = *(const bf16x8*)&Bs[wc * 64 + n * 16 + lrow][kk * 32 + lhi * 8];
#pragma unroll
      for (int m = 0; m < 4; ++m)
#pragma unroll
        for (int n = 0; n < 4; ++n)
          acc[m][n] = __builtin_amdgcn_mfma_f32_16x16x32_bf16(af[m], bfr[n], acc[m][n], 0, 0, 0);
    }
    __syncthreads();
  }

#pragma unroll
  for (int m = 0; m < 4; ++m) {
#pragma unroll
    for (int n = 0; n < 4; ++n) {
      const int row = row0 + wr * 64 + m * 16 + lhi * 4;
      const int col = col0 + wc * 64 + n * 16 + lrow;
#pragma unroll
      for (int r = 0; r < 4; ++r)
        out[(size_t)(row + r) * OUTF + col] = acc[m][n][r];
    }
  }
}

extern "C" void kernel_launch(void* const* d_in, const int* in_sizes, int n_in,
                              void* d_out, int out_size, void* d_ws, size_t ws_size,
                              hipStream_t stream) {
  const float* x   = (const float*)d_in[0];
  const float* w_b = (const float*)d_in[1];
  const float* w_s = (const float*)d_in[2];
  const float* c   = (const float*)d_in[3];
  float* out = (float*)d_out;

  const size_t need = (size_t)OUTF * KTOT * sizeof(unsigned short);  // 10.1 MiB
  if (ws_size >= need) {
    unsigned short* bext = (unsigned short*)d_ws;
    build_bext<<<(OUTF * KTOT / 8) / 256, 256, 0, stream>>>(w_b, w_s, c, bext);
    kan_gemm5<<<(BATCH / BM) * (OUTF / BN), 256, 0, stream>>>(x, bext, out);
  } else {
    kan_gemm_fb<<<(BATCH / BM) * (OUTF / BN), 256, 0, stream>>>(x, w_b, w_s, c, out);
  }
}